// Round 4
// baseline (73.093 us; speedup 1.0000x reference)
//
#include <hip/hip_runtime.h>

// Depthwise conv1d along L, K=25, replicate padding, + scalar bias.
// x: [B=32, L=2048, C=512] f32 -> out same shape.
// out[b,l,c] = sum_k w[k] * x[b, clamp(l+k-12, 0, L-1), c] + bias
//
// R3: memory-level-parallelism fix. R2 showed occupancy 65% but BW stuck at
// ~4.3 TB/s -> each wave had ~1 load in flight (36 VGPR). Now: groups of 8
// rows double-buffered in named register arrays (static indexing only),
// 8-16 loads outstanding per wave. Plain stores (NT store de-confound).

typedef float f32x4 __attribute__((ext_vector_type(4)));

constexpr int K      = 25;
constexpr int HALF   = 12;
constexpr int LCHUNK = 8;
constexpr int BB     = 32;
constexpr int LL     = 2048;
constexpr int CC     = 512;
constexpr int C4     = CC / 4;            // 128 f32x4 per row
constexpr int NCHUNK = LL / LCHUNK;       // 256
constexpr int NBLK   = BB * NCHUNK * C4 / 256;  // 4096 blocks
constexpr int NROWS  = LCHUNK + K - 1;    // 32
constexpr int G      = 8;                 // rows per load group

__global__ __launch_bounds__(256) void conv1d_dw_kernel(
    const float* __restrict__ x,
    const float* __restrict__ w,
    const float* __restrict__ bias_p,
    float* __restrict__ out)
{
    // XCD-aware swizzle: contiguous logical-block (L-range) runs per XCD.
    const int bid  = blockIdx.x;
    const int lbid = (bid & 7) * (NBLK >> 3) + (bid >> 3);

    const int tid   = lbid * 256 + threadIdx.x;
    const int c4    = tid & (C4 - 1);          // 0..127
    const int rest  = tid >> 7;
    const int chunk = rest & (NCHUNK - 1);     // 0..255
    const int b     = rest >> 8;               // 0..31

    float wr[K];
#pragma unroll
    for (int k = 0; k < K; ++k) wr[k] = w[k];  // wave-uniform -> SGPR
    const float bias = bias_p[0];

    const int l0 = chunk * LCHUNK;
    const f32x4* xb = reinterpret_cast<const f32x4*>(x) + (size_t)b * LL * C4;
    f32x4*       ob = reinterpret_cast<f32x4*>(out)
                      + (size_t)b * LL * C4 + (size_t)l0 * C4 + c4;

    f32x4 acc[LCHUNK];
#pragma unroll
    for (int j = 0; j < LCHUNK; ++j)
        acc[j] = (f32x4){bias, bias, bias, bias};

    // row r (0..31) -> clamped source pointer
#define ROWPTR(r) (xb + (size_t)max(0, min(LL - 1, l0 + (r) - HALF)) * C4 + c4)

#define LOAD_GROUP(buf, g)                                   \
    _Pragma("unroll")                                        \
    for (int i = 0; i < G; ++i) buf[i] = *ROWPTR((g) * G + i);

#define FMA_GROUP(buf, g)                                    \
    _Pragma("unroll")                                        \
    for (int i = 0; i < G; ++i) {                            \
        const int r = (g) * G + i;                           \
        _Pragma("unroll")                                    \
        for (int j = 0; j < LCHUNK; ++j) {                   \
            const int k = r - j;                             \
            if (k >= 0 && k < K) acc[j] += wr[k] * buf[i];   \
        }                                                    \
    }

    f32x4 bufA[G], bufB[G];
    LOAD_GROUP(bufA, 0);          // 8 loads outstanding
    LOAD_GROUP(bufB, 1);          // 16 outstanding
    FMA_GROUP(bufA, 0);           // waits vmcnt(8), consumes group 0
    LOAD_GROUP(bufA, 2);          // refill -> 16 outstanding again
    FMA_GROUP(bufB, 1);
    LOAD_GROUP(bufB, 3);
    FMA_GROUP(bufA, 2);
    FMA_GROUP(bufB, 3);

#undef ROWPTR
#undef LOAD_GROUP
#undef FMA_GROUP

#pragma unroll
    for (int j = 0; j < LCHUNK; ++j)
        ob[(size_t)j * C4] = acc[j];
}

extern "C" void kernel_launch(void* const* d_in, const int* in_sizes, int n_in,
                              void* d_out, int out_size, void* d_ws, size_t ws_size,
                              hipStream_t stream) {
    const float* x  = (const float*)d_in[0];
    const float* w  = (const float*)d_in[1];
    const float* bp = (const float*)d_in[2];
    float* out      = (float*)d_out;

    conv1d_dw_kernel<<<NBLK, 256, 0, stream>>>(x, w, bp, out);
}

// Round 5
// 48.136 us; speedup vs baseline: 1.5185x; 1.5185x over previous
//
#include <hip/hip_runtime.h>
#include <stdint.h>

// Depthwise conv1d along L, K=25, replicate padding, + scalar bias.
// x: [B=32, L=2048, C=512] f32 -> out same shape.
//
// R4: decouple global loads from the FMA chain. R3 showed the compiler
// re-serializes any register-resident load stream (VGPR stayed 36). Now each
// block stages its 56 input rows (32-output tile + 24 halo, half-C width)
// into LDS via global_load_lds width=16 (no VGPR round trip; 14 loads
// issued back-to-back per wave -> ~56KB in flight per block), then computes
// from LDS via ds_read_b128. NT stores kept (R2/R3 A/B: -48MB FETCH).

typedef float f32x4 __attribute__((ext_vector_type(4)));

constexpr int K      = 25;
constexpr int HALF   = 12;
constexpr int BB     = 32;
constexpr int LL     = 2048;
constexpr int CC     = 512;
constexpr int TL     = 32;                 // outputs (l) per block
constexpr int NROWS  = TL + K - 1;         // 56 staged rows
constexpr int HC4    = 64;                 // half-C in f32x4 units
constexpr int NTILE  = LL / TL;            // 64
constexpr int NBLK   = BB * NTILE * 2;     // 4096 blocks

__device__ inline void gll16(const float* g, float* l) {
    __builtin_amdgcn_global_load_lds(
        (const __attribute__((address_space(1))) void*)g,
        (__attribute__((address_space(3))) void*)l, 16, 0, 0);
}

__global__ __launch_bounds__(256) void conv1d_dw_kernel(
    const float* __restrict__ x,
    const float* __restrict__ w,
    const float* __restrict__ bias_p,
    float* __restrict__ out)
{
    __shared__ float lds[NROWS * HC4 * 4];   // 56 rows x 64 f32x4 = 56 KB

    // XCD-aware swizzle: contiguous logical-block runs per XCD.
    const int bid  = blockIdx.x;
    const int lbid = (bid & 7) * (NBLK >> 3) + (bid >> 3);

    // adjacent lbid = adjacent ltile, same C-half -> halo L2 reuse
    const int ltile = lbid & (NTILE - 1);
    const int half  = (lbid >> 6) & 1;
    const int b     = lbid >> 7;

    const int tid  = threadIdx.x;
    const int wv   = tid >> 6;               // 0..3
    const int lane = tid & 63;

    const int l0 = ltile * TL;
    const size_t base = (size_t)b * LL * CC + (size_t)half * (HC4 * 4);

    // ---- stage 56 rows x 1KB into LDS (14 gll per wave) ----
#pragma unroll
    for (int i = 0; i < NROWS / 4; ++i) {
        const int r    = wv * (NROWS / 4) + i;
        const int srcl = max(0, min(LL - 1, l0 - HALF + r));
        gll16(x + base + (size_t)srcl * CC + lane * 4, &lds[(r * HC4 + lane) * 4]);
    }

    // weights / bias (wave-uniform -> SGPR)
    float wr[K];
#pragma unroll
    for (int k = 0; k < K; ++k) wr[k] = w[k];
    const float bias = bias_p[0];

    __syncthreads();   // drains vmcnt before barrier (compiler-enforced)

    // ---- compute: thread = (c4 = lane, sub = wave), 8 outputs ----
    f32x4 acc[8];
#pragma unroll
    for (int j = 0; j < 8; ++j)
        acc[j] = (f32x4){bias, bias, bias, bias};

    const f32x4* ldsv = reinterpret_cast<const f32x4*>(lds);
#pragma unroll
    for (int rr = 0; rr < 32; ++rr) {
        const f32x4 v = ldsv[(wv * 8 + rr) * HC4 + lane];
#pragma unroll
        for (int j = 0; j < 8; ++j) {
            const int k = rr - j;            // compile-time per (rr,j)
            if (k >= 0 && k < K) acc[j] += wr[k] * v;
        }
    }

    f32x4* ob = reinterpret_cast<f32x4*>(out + base) + (size_t)(l0 + wv * 8) * (CC / 4) + lane;
#pragma unroll
    for (int j = 0; j < 8; ++j)
        __builtin_nontemporal_store(acc[j], &ob[(size_t)j * (CC / 4)]);
}

extern "C" void kernel_launch(void* const* d_in, const int* in_sizes, int n_in,
                              void* d_out, int out_size, void* d_ws, size_t ws_size,
                              hipStream_t stream) {
    const float* x  = (const float*)d_in[0];
    const float* w  = (const float*)d_in[1];
    const float* bp = (const float*)d_in[2];
    float* out      = (float*)d_out;

    conv1d_dw_kernel<<<NBLK, 256, 0, stream>>>(x, w, bp, out);
}